// Round 2
// baseline (827.678 us; speedup 1.0000x reference)
//
#include <hip/hip_runtime.h>

// Problem constants (from reference)
#define PP 712740      // M*K points
#define MM 35637       // M
#define KK 20          // K neighbors
#define NF 15872       // N points in x_feat
#define NTILES 44547   // ceil(PP/16) point-tiles of 16
#define NSUPER 11137   // ceil(PP/64) supertiles of 64 points
// FEAT = 128 channels, W0 = 1.0, EPS = 1e-5

typedef _Float16 h16;
typedef __attribute__((ext_vector_type(4))) _Float16 f16x4;
typedef __attribute__((ext_vector_type(8))) _Float16 f16x8;
typedef __attribute__((ext_vector_type(4))) float f32x4;

// ---------------------------------------------------------------------------
// Zero the stats accumulators (8 layers x 256 doubles).
// ---------------------------------------------------------------------------
__global__ __launch_bounds__(256) void k_zero(double* __restrict__ gs) {
  const int t = threadIdx.x;
#pragma unroll
  for (int i = 0; i < 8; ++i) gs[i * 256 + t] = 0.0;
}

// ---------------------------------------------------------------------------
// Layer 0 (K=7, VALU): z0[p][c] = sum_c7 w0[c][c7] * up[c7][p], z point-major
// f16 [PP][128]. (unchanged)
// ---------------------------------------------------------------------------
__global__ __launch_bounds__(256) void k_layer0(
    const float* __restrict__ up,    // [7][PP]
    const float* __restrict__ w0,    // [128][7]
    h16* __restrict__ z,             // [PP][128]
    double* __restrict__ gs)         // [256]: sum[128], sumsq[128]
{
  __shared__ float w0s[128 * 7];
  __shared__ double red[4][256];
  const int t = threadIdx.x;
  for (int i = t; i < 128 * 7; i += 256) w0s[i] = w0[i];
  __syncthreads();

  const int w = t >> 6;
  const int lane = t & 63;
  const int ln = lane & 15;
  const int q = lane >> 4;

  float sp[32], qp[32];
#pragma unroll
  for (int i = 0; i < 32; ++i) { sp[i] = 0.f; qp[i] = 0.f; }

  const int gw = blockIdx.x * 4 + w;
  for (int tile = gw; tile < NTILES; tile += gridDim.x * 4) {
    const int p = tile * 16 + ln;
    const bool act = p < PP;
    float u[7];
#pragma unroll
    for (int c7 = 0; c7 < 7; ++c7) u[c7] = act ? up[c7 * PP + p] : 0.f;

#pragma unroll
    for (int ks = 0; ks < 4; ++ks) {
      f16x8 o;
#pragma unroll
      for (int j = 0; j < 8; ++j) {
        const int c = ks * 32 + q * 8 + j;
        float acc = 0.f;
#pragma unroll
        for (int c7 = 0; c7 < 7; ++c7) acc = fmaf(w0s[c * 7 + c7], u[c7], acc);
        o[j] = (h16)acc;
        const int si = ks * 8 + j;
        sp[si] += acc;
        qp[si] = fmaf(acc, acc, qp[si]);
      }
      if (act) *(f16x8*)(z + (size_t)p * 128 + ks * 32 + q * 8) = o;
    }
  }

#pragma unroll
  for (int i = 0; i < 32; ++i) {
#pragma unroll
    for (int d = 1; d < 16; d <<= 1) {
      sp[i] += __shfl_xor(sp[i], d, 64);
      qp[i] += __shfl_xor(qp[i], d, 64);
    }
  }
  if (ln == 0) {
#pragma unroll
    for (int ks = 0; ks < 4; ++ks)
#pragma unroll
      for (int j = 0; j < 8; ++j) {
        const int c = ks * 32 + q * 8 + j;
        red[w][c] = (double)sp[ks * 8 + j];
        red[w][128 + c] = (double)qp[ks * 8 + j];
      }
  }
  __syncthreads();
  double v = red[0][t] + red[1][t] + red[2][t] + red[3][t];
  atomicAdd(&gs[t], v);
}

// ---------------------------------------------------------------------------
// Middle layer (x7), MFMA, block-cooperative 64-point SUPERTILES.
//   Same fragment/swizzle/store math as the verified 16-pt version, but the
//   block-wide barrier is amortized over 4x the work: per iteration each
//   thread activates 4 f16x8 chunks into a 16KB LDS act tile, then each
//   wave runs 32 MFMAs (4 subtiles x 2 nt x 4 ks) against its persistent
//   32-VGPR W fragments. Depth-1 register prefetch of the next supertile
//   crosses the (lgkmcnt-only) barrier; vmcnt never drained in-loop.
// ---------------------------------------------------------------------------
__global__ __launch_bounds__(256, 3) void k_layer(
    h16* __restrict__ z,              // [PP][128], in-place
    const double* __restrict__ gsp,   // stats of previous layer output
    double* __restrict__ gso,         // stats of this layer output
    const float* __restrict__ W,      // [128][128] fp32
    const float* __restrict__ gamma,  // [128]
    const float* __restrict__ beta)   // [128]
{
  __shared__ h16 act[2][8192];        // 2 x (64 pts x 128 ch), XOR-swizzled
  __shared__ double red[256];

  const int t = threadIdx.x;
  const int w = t >> 6;
  const int lane = t & 63;
  const int ln = lane & 15;
  const int q = lane >> 4;
  const int G = (int)gridDim.x;

  // BN consts for this thread's 8 activation channels: c = (t&15)*8 + j
  float sc[8], sh[8];
  {
    const double n = (double)PP;
    const int cb = (t & 15) * 8;
#pragma unroll
    for (int j = 0; j < 8; ++j) {
      const int c = cb + j;
      const double mu = gsp[c] / n;
      const double var = gsp[128 + c] / n - mu * mu;
      const float rstd = (float)(1.0 / sqrt(var + 1e-5));
      sc[j] = rstd * gamma[c];
      sh[j] = beta[c] - (float)mu * sc[j];
    }
  }

  // Persistent W fragments (A-operand), wave w owns channels [w*32, w*32+32).
  // Permuted row mapping: fragment-row rr of mfma nt <-> channel
  // ob + (rr>>2)*8 + nt*4 + (rr&3)  => lane owns channels ob+q*8 .. +7.
  const int ob = w * 32;
  f16x8 wfr[2][4];
#pragma unroll
  for (int nt = 0; nt < 2; ++nt) {
    const int row_g = ob + (ln >> 2) * 8 + nt * 4 + (ln & 3);
    const float* wrow = W + (size_t)row_g * 128;
#pragma unroll
    for (int ks = 0; ks < 4; ++ks) {
      const float* src = wrow + ks * 32 + q * 8;
      const float4 aa = *(const float4*)src;
      const float4 bb = *(const float4*)(src + 4);
      f16x8 b;
      b[0] = (h16)aa.x; b[1] = (h16)aa.y; b[2] = (h16)aa.z; b[3] = (h16)aa.w;
      b[4] = (h16)bb.x; b[5] = (h16)bb.y; b[6] = (h16)bb.z; b[7] = (h16)bb.w;
      wfr[nt][ks] = b;
    }
  }

  float sp[8], qp[8];
#pragma unroll
  for (int i = 0; i < 8; ++i) { sp[i] = 0.f; qp[i] = 0.f; }

  // Per-thread raw chunks: point (t>>4)+16s (s=0..3), channels (t&15)*8..+7.
  const size_t roff = (size_t)(t >> 4) * 128 + (size_t)(t & 15) * 8;
  const int wbase = ((t >> 4) * 256 + (t & 15) * 16) ^ (((t >> 4) & 7) << 4);
  int raddr[4];
#pragma unroll
  for (int ks = 0; ks < 4; ++ks)
    raddr[ks] = (ln * 256 + ks * 64 + q * 16) ^ ((ln & 7) << 4);

  int stile = blockIdx.x;
  f16x8 raw[4];
  {
    const h16* src = z + (size_t)stile * 8192 + roff;
#pragma unroll
    for (int s = 0; s < 4; ++s) raw[s] = *(const f16x8*)(src + s * 2048);
  }
  int ib = 0;

  for (; stile < NSUPER; stile += G) {
    char* ab = (char*)(&act[ib][0]);

    // BN + sine on this thread's 4 chunks (computed once per element),
    // straight into the swizzled LDS act tile; raw regs die here.
#pragma unroll
    for (int s = 0; s < 4; ++s) {
      f16x8 av;
#pragma unroll
      for (int j = 0; j < 8; ++j)
        av[j] = (h16)__sinf(fmaf((float)raw[s][j], sc[j], sh[j]));
      *(f16x8*)(ab + (wbase + s * 4096)) = av;
    }

    // depth-1 prefetch of next supertile into the freed raw regs
    {
      const int nxt = (stile + G < NSUPER) ? stile + G : NSUPER - 1;
      const h16* src = z + (size_t)nxt * 8192 + roff;
#pragma unroll
      for (int s = 0; s < 4; ++s) raw[s] = *(const f16x8*)(src + s * 2048);
    }

    // LDS-only barrier: do NOT drain vmcnt (prefetch stays in flight).
    asm volatile("s_waitcnt lgkmcnt(0)\n\ts_barrier" ::: "memory");

#pragma unroll
    for (int ot = 0; ot < 4; ++ot) {
      f16x8 afr[4];
#pragma unroll
      for (int ks = 0; ks < 4; ++ks)
        afr[ks] = *(const f16x8*)(ab + (ot * 4096 + raddr[ks]));

      f32x4 acc0 = (f32x4){0.f, 0.f, 0.f, 0.f};
      f32x4 acc1 = (f32x4){0.f, 0.f, 0.f, 0.f};
#pragma unroll
      for (int ks = 0; ks < 4; ++ks) {
        acc0 = __builtin_amdgcn_mfma_f32_16x16x32_f16(wfr[0][ks], afr[ks], acc0, 0, 0, 0);
        acc1 = __builtin_amdgcn_mfma_f32_16x16x32_f16(wfr[1][ks], afr[ks], acc1, 0, 0, 0);
      }

      // D[channel][point]: lane (q,ln) holds ch ob+q*8..+7 of point ot*16+ln
      const int p = stile * 64 + ot * 16 + ln;
      if (p < PP) {
        f16x8 o;
        o[0] = (h16)acc0[0]; o[1] = (h16)acc0[1]; o[2] = (h16)acc0[2]; o[3] = (h16)acc0[3];
        o[4] = (h16)acc1[0]; o[5] = (h16)acc1[1]; o[6] = (h16)acc1[2]; o[7] = (h16)acc1[3];
        *(f16x8*)(z + (size_t)p * 128 + ob + q * 8) = o;
#pragma unroll
        for (int r = 0; r < 4; ++r) {
          sp[r]     += acc0[r];
          qp[r]      = fmaf(acc0[r], acc0[r], qp[r]);
          sp[4 + r] += acc1[r];
          qp[4 + r]  = fmaf(acc1[r], acc1[r], qp[4 + r]);
        }
      }
    }
    ib ^= 1;
  }

  // stats: reduce over the 16 ln lanes; sp[r]<->ch ob+q*8+r, sp[4+r]<->+4
#pragma unroll
  for (int i = 0; i < 8; ++i) {
#pragma unroll
    for (int d = 1; d < 16; d <<= 1) {
      sp[i] += __shfl_xor(sp[i], d, 64);
      qp[i] += __shfl_xor(qp[i], d, 64);
    }
  }
  if (ln == 0) {
#pragma unroll
    for (int r = 0; r < 4; ++r) {
      const int c = ob + q * 8 + r;
      red[c]           = (double)sp[r];
      red[c + 4]       = (double)sp[4 + r];
      red[128 + c]     = (double)qp[r];
      red[128 + c + 4] = (double)qp[4 + r];
    }
  }
  __syncthreads();
  atomicAdd(&gso[t], red[t]);
}

// ---------------------------------------------------------------------------
// Fused final conv (128->1, BN7+sine) + softmax over K=20 + gather-weighted
// sum. One wave per m. (unchanged)
// ---------------------------------------------------------------------------
__global__ __launch_bounds__(256) void k_outf(
    const h16* __restrict__ z,         // [PP][128]
    const double* __restrict__ gsp,    // stats of layer-7 output
    const float* __restrict__ gamma,   // [128] (layer 7)
    const float* __restrict__ beta,    // [128]
    const float* __restrict__ fw,      // [128]
    const float* __restrict__ fb,      // [1]
    const int* __restrict__ idx,       // [MM][KK]
    const float* __restrict__ xf,      // [NF][128]
    float* __restrict__ out)           // [MM][128]
{
  const int gw = (int)((blockIdx.x * 256 + threadIdx.x) >> 6);
  const int lane = (int)(threadIdx.x & 63);
  if (gw >= MM) return;
  const int m = gw;
  const int c0 = lane * 2;

  float scv[2], shv[2], fv[2];
#pragma unroll
  for (int j = 0; j < 2; ++j) {
    const int c = c0 + j;
    const double n = (double)PP;
    const double mu = gsp[c] / n;
    const double var = gsp[128 + c] / n - mu * mu;
    const float rstd = (float)(1.0 / sqrt(var + 1e-5));
    scv[j] = rstd * gamma[c];
    shv[j] = beta[c] - (float)mu * scv[j];
    fv[j] = fw[c];
  }
  const float fbv = fb[0];

  float l[KK];
#pragma unroll
  for (int k = 0; k < KK; ++k) {
    const h16* zp = z + (size_t)(m * KK + k) * 128 + c0;
    float part = fv[0] * __sinf(fmaf((float)zp[0], scv[0], shv[0]))
               + fv[1] * __sinf(fmaf((float)zp[1], scv[1], shv[1]));
#pragma unroll
    for (int d = 1; d < 64; d <<= 1) part += __shfl_xor(part, d, 64);
    l[k] = part + fbv;
  }

  float mx = l[0];
#pragma unroll
  for (int k = 1; k < KK; ++k) mx = fmaxf(mx, l[k]);
  float ssum = 0.f;
#pragma unroll
  for (int k = 0; k < KK; ++k) { l[k] = __expf(l[k] - mx); ssum += l[k]; }
  const float inv = 1.f / ssum;

  float a0 = 0.f, a1 = 0.f;
#pragma unroll
  for (int k = 0; k < KK; ++k) {
    const int r = idx[m * KK + k];
    const float wk = l[k] * inv;
    a0 = fmaf(wk, xf[r * 128 + lane], a0);
    a1 = fmaf(wk, xf[r * 128 + 64 + lane], a1);
  }
  out[m * 128 + lane] = a0;
  out[m * 128 + 64 + lane] = a1;
}

// ---------------------------------------------------------------------------
// Softmax over K=20 per m + gather (logits-array version, fallback path).
// ---------------------------------------------------------------------------
__global__ __launch_bounds__(256) void k_out(
    const float* __restrict__ logits,  // [PP]
    const int* __restrict__ idx,       // [MM][KK]
    const float* __restrict__ xf,      // [NF][128]
    float* __restrict__ out)           // [MM][128]
{
  const int gw = (int)((blockIdx.x * 256 + threadIdx.x) >> 6);
  const int lane = threadIdx.x & 63;
  if (gw >= MM) return;
  const int m = gw;

  float l[KK];
#pragma unroll
  for (int k = 0; k < KK; ++k) l[k] = logits[m * KK + k];
  float mx = l[0];
#pragma unroll
  for (int k = 1; k < KK; ++k) mx = fmaxf(mx, l[k]);
  float ssum = 0.f;
#pragma unroll
  for (int k = 0; k < KK; ++k) { l[k] = __expf(l[k] - mx); ssum += l[k]; }
  const float inv = 1.f / ssum;

  float a0 = 0.f, a1 = 0.f;
#pragma unroll
  for (int k = 0; k < KK; ++k) {
    const int r = idx[m * KK + k];
    const float wk = l[k] * inv;
    a0 = fmaf(wk, xf[r * 128 + lane], a0);
    a1 = fmaf(wk, xf[r * 128 + 64 + lane], a1);
  }
  out[m * 128 + lane] = a0;
  out[m * 128 + 64 + lane] = a1;
}

// ---------------------------------------------------------------------------
// Fallback (small workspace): recompute chain in registers per point.
// ---------------------------------------------------------------------------
__global__ __launch_bounds__(256) void k_chain(
    const float* __restrict__ up,
    const float* __restrict__ w0,
    const float* __restrict__ wc,
    const float* __restrict__ gam,
    const float* __restrict__ bet,
    const double* __restrict__ gs,
    double* __restrict__ gso,
    int jl, int mode,
    const float* __restrict__ fw,
    const float* __restrict__ fb,
    float* __restrict__ logits)
{
  __shared__ float sc_s[8][128], sh_s[8][128];
  __shared__ double bred[4][256];
  const int t = threadIdx.x;
  const int lane = t & 63;

  const int nbn = (mode == 0) ? jl : 8;
  for (int i = t; i < nbn * 128; i += 256) {
    const int L = i >> 7, c = i & 127;
    const double n = (double)PP;
    const double mu = gs[L * 256 + c] / n;
    const double var = gs[L * 256 + 128 + c] / n - mu * mu;
    const float rstd = (float)(1.0 / sqrt(var + 1e-5));
    const float sc = rstd * gam[L * 128 + c];
    sc_s[L][c] = sc;
    sh_s[L][c] = bet[L * 128 + c] - (float)mu * sc;
  }
  __syncthreads();

  double lS0 = 0, lS1 = 0, lQ0 = 0, lQ1 = 0;

  for (int p0 = blockIdx.x * 256; p0 < PP; p0 += gridDim.x * 256) {
    const int p = p0 + t;
    const bool act = p < PP;

    float a[128];
    {
      float u[7];
#pragma unroll
      for (int c = 0; c < 7; ++c) u[c] = act ? up[c * PP + p] : 0.f;
#pragma unroll 1
      for (int och = 0; och < 16; ++och) {
#pragma unroll
        for (int j = 0; j < 8; ++j) {
          float acc = 0.f;
#pragma unroll
          for (int c = 0; c < 7; ++c)
            acc = fmaf(w0[(och * 8 + j) * 7 + c], u[c], acc);
          a[och * 8 + j] = acc;
        }
      }
    }

#pragma unroll 1
    for (int L = 0; L < jl; ++L) {
#pragma unroll
      for (int c = 0; c < 128; ++c)
        a[c] = act ? __sinf(fmaf(a[c], sc_s[L][c], sh_s[L][c])) : 0.f;
      float b[128];
      const float* W = wc + (size_t)L * 128 * 128;
#pragma unroll 1
      for (int och = 0; och < 16; ++och) {
#pragma unroll
        for (int j = 0; j < 8; ++j) {
          float acc = 0.f;
#pragma unroll
          for (int c = 0; c < 128; ++c)
            acc = fmaf(W[(och * 8 + j) * 128 + c], a[c], acc);
          b[och * 8 + j] = acc;
        }
      }
#pragma unroll
      for (int c = 0; c < 128; ++c) a[c] = b[c];
    }

    if (mode == 0) {
#pragma unroll
      for (int o = 0; o < 128; ++o) {
        float s = a[o];
        float qv = a[o] * a[o];
#pragma unroll
        for (int d = 32; d > 0; d >>= 1) {
          s += __shfl_xor(s, d, 64);
          qv += __shfl_xor(qv, d, 64);
        }
        if ((o & 63) == lane) {
          if (o < 64) { lS0 += (double)s; lQ0 += (double)qv; }
          else        { lS1 += (double)s; lQ1 += (double)qv; }
        }
      }
    } else if (act) {
      float acc = fb[0];
#pragma unroll
      for (int c = 0; c < 128; ++c) {
        const float h = fmaf(a[c], sc_s[7][c], sh_s[7][c]);
        acc = fmaf(fw[c], __sinf(h), acc);
      }
      logits[p] = acc;
    }
  }

  if (mode == 0) {
    const int w = t >> 6;
    bred[w][lane]       = lS0;
    bred[w][64 + lane]  = lS1;
    bred[w][128 + lane] = lQ0;
    bred[w][192 + lane] = lQ1;
    __syncthreads();
    double v = bred[0][t] + bred[1][t] + bred[2][t] + bred[3][t];
    atomicAdd(&gso[t], v);
  }
}

// ---------------------------------------------------------------------------
extern "C" void kernel_launch(void* const* d_in, const int* in_sizes, int n_in,
                              void* d_out, int out_size, void* d_ws, size_t ws_size,
                              hipStream_t stream) {
  const float* xf  = (const float*)d_in[0];  // (1, N, 128)
  const float* up  = (const float*)d_in[1];  // (1, 7, M, K)  == [7][PP]
  const int*   idx = (const int*)d_in[2];    // (1, M, K)
  const float* w0  = (const float*)d_in[3];  // (128, 7)
  const float* wc  = (const float*)d_in[4];  // (7, 128, 128)
  const float* gam = (const float*)d_in[5];  // (8, 128)
  const float* bet = (const float*)d_in[6];  // (8, 128)
  const float* fw  = (const float*)d_in[7];  // (1, 128)
  const float* fb  = (const float*)d_in[8];  // (1,)
  float* out = (float*)d_out;

  char* ws = (char*)d_ws;
  const size_t zb     = (size_t)PP * 128 * sizeof(h16);   // 182,461,440 B
  const size_t statsb = 8 * 256 * sizeof(double);         // 16,384 B
  const size_t logb   = (size_t)PP * sizeof(float);       // 2,850,960 B
  const int NB = 1024;
  const int nbo = (MM + 3) / 4;

  if (ws_size >= zb + statsb + logb) {
    // Fast path: point-major fp16 z + cooperative MFMA layers.
    h16* z = (h16*)ws;
    double* gs = (double*)(ws + zb);

    k_zero<<<1, 256, 0, stream>>>(gs);
    k_layer0<<<NB, 256, 0, stream>>>(up, w0, z, gs);
    for (int i = 1; i <= 7; ++i) {
      k_layer<<<NB, 256, 0, stream>>>(z,
                                      gs + (size_t)(i - 1) * 256,
                                      gs + (size_t)i * 256,
                                      wc + (size_t)(i - 1) * 128 * 128,
                                      gam + (size_t)(i - 1) * 128,
                                      bet + (size_t)(i - 1) * 128);
    }
    k_outf<<<nbo, 256, 0, stream>>>(z, gs + 7 * 256, gam + 7 * 128,
                                    bet + 7 * 128, fw, fb, idx, xf, out);
  } else {
    // Fallback: recompute chain, needs only ~2.9 MiB of workspace.
    double* gs = (double*)ws;
    float* logits = (float*)(ws + statsb);

    k_zero<<<1, 256, 0, stream>>>(gs);
    for (int j = 0; j <= 7; ++j) {
      k_chain<<<NB, 256, 0, stream>>>(up, w0, wc, gam, bet, gs,
                                      gs + (size_t)j * 256, j, 0,
                                      fw, fb, logits);
    }
    k_chain<<<NB, 256, 0, stream>>>(up, w0, wc, gam, bet, gs,
                                    nullptr, 7, 1, fw, fb, logits);
    k_out<<<nbo, 256, 0, stream>>>(logits, idx, xf, out);
  }
}

// Round 4
// 713.741 us; speedup vs baseline: 1.1596x; 1.1596x over previous
//
#include <hip/hip_runtime.h>

// Problem constants (from reference)
#define PP 712740      // M*K points
#define MM 35637       // M
#define KK 20          // K neighbors
#define NF 15872       // N points in x_feat
#define NTILES 44547   // ceil(PP/16) point-tiles of 16
#define NSUPER 11137   // ceil(PP/64) supertiles of 64 points
#define ZROWS (NSUPER * 64)   // 712768 padded rows (z buffers sized to this)
// FEAT = 128 channels, W0 = 1.0, EPS = 1e-5

typedef _Float16 h16;
typedef __attribute__((ext_vector_type(8))) _Float16 f16x8;
typedef __attribute__((ext_vector_type(4))) float f32x4;

// ---------------------------------------------------------------------------
// Zero the stats accumulators (8 layers x 256 doubles).
// ---------------------------------------------------------------------------
__global__ __launch_bounds__(256) void k_zero(double* __restrict__ gs) {
  const int t = threadIdx.x;
#pragma unroll
  for (int i = 0; i < 8; ++i) gs[i * 256 + t] = 0.0;
}

// ---------------------------------------------------------------------------
// Layer 0 (K=7, VALU): z0[p][c] = sum_c7 w0[c][c7] * up[c7][p], z point-major
// f16 [ZROWS][128]. Writes routed through a per-wave 4KB LDS tile so each
// store instruction is 1KB contiguous (was 16 rows x 64B scatter). Pad rows
// (PP..ZROWS) are written with zeros so downstream reads are defined.
// ---------------------------------------------------------------------------
__global__ __launch_bounds__(256) void k_layer0(
    const float* __restrict__ up,    // [7][PP]
    const float* __restrict__ w0,    // [128][7]
    h16* __restrict__ z,             // [ZROWS][128]
    double* __restrict__ gs)         // [256]: sum[128], sumsq[128]
{
  __shared__ float w0s[128 * 7];
  __shared__ h16 tb[4][2048];        // per-wave 16 pts x 128 ch, XOR-swizzled
  __shared__ double red[4][256];
  const int t = threadIdx.x;
  for (int i = t; i < 128 * 7; i += 256) w0s[i] = w0[i];
  __syncthreads();

  const int w = t >> 6;
  const int lane = t & 63;
  const int ln = lane & 15;
  const int q = lane >> 4;

  float sp[32], qp[32];
#pragma unroll
  for (int i = 0; i < 32; ++i) { sp[i] = 0.f; qp[i] = 0.f; }

  h16* tbw = &tb[w][0];

  const int gw = blockIdx.x * 4 + w;
  for (int tile = gw; tile < NTILES; tile += gridDim.x * 4) {
    const int p = tile * 16 + ln;
    const bool act = p < PP;
    float u[7];
#pragma unroll
    for (int c7 = 0; c7 < 7; ++c7) u[c7] = act ? up[c7 * PP + p] : 0.f;

#pragma unroll
    for (int ks = 0; ks < 4; ++ks) {
      f16x8 o;
#pragma unroll
      for (int j = 0; j < 8; ++j) {
        const int c = ks * 32 + q * 8 + j;
        float acc = 0.f;
#pragma unroll
        for (int c7 = 0; c7 < 7; ++c7) acc = fmaf(w0s[c * 7 + c7], u[c7], acc);
        if (!act) acc = 0.f;         // pad rows -> zeros
        o[j] = (h16)acc;
        const int si = ks * 8 + j;
        sp[si] += acc;
        qp[si] = fmaf(acc, acc, qp[si]);
      }
      *(f16x8*)(tbw + ln * 128 + (((ks * 4 + q) ^ (ln & 7)) << 3)) = o;
    }

    // readback + 1KB-contiguous stores (wave-private tile; compiler orders
    // the ds_read after the ds_write via lgkmcnt deps). Pad rows stored too
    // (zeros) - buffer is ZROWS, always in-bounds.
#pragma unroll
    for (int pass = 0; pass < 4; ++pass) {
      const int c = pass * 64 + lane;
      const int r = c >> 4;
      const int k = c & 15;
      const f16x8 v = *(const f16x8*)(tbw + r * 128 + ((k ^ (r & 7)) << 3));
      *(f16x8*)(z + (size_t)tile * 2048 + (size_t)c * 8) = v;
    }
  }

#pragma unroll
  for (int i = 0; i < 32; ++i) {
#pragma unroll
    for (int d = 1; d < 16; d <<= 1) {
      sp[i] += __shfl_xor(sp[i], d, 64);
      qp[i] += __shfl_xor(qp[i], d, 64);
    }
  }
  if (ln == 0) {
#pragma unroll
    for (int ks = 0; ks < 4; ++ks)
#pragma unroll
      for (int j = 0; j < 8; ++j) {
        const int c = ks * 32 + q * 8 + j;
        red[w][c] = (double)sp[ks * 8 + j];
        red[w][128 + c] = (double)qp[ks * 8 + j];
      }
  }
  __syncthreads();
  double v = red[0][t] + red[1][t] + red[2][t] + red[3][t];
  atomicAdd(&gs[t], v);
}

// ---------------------------------------------------------------------------
// Middle layer (x7), MFMA, block-cooperative 64-point SUPERTILES.
//   Fixed-role LDS buffers: A = sine-activated inputs (MFMA operands),
//   B = MFMA outputs staged for a coalescing re-tile. BOTH global streams
//   are 1KB contiguous per wave instruction. 2 raw barriers per supertile
//   (lgkmcnt-only drains; global prefetch stays in flight):
//     bar1: A complete -> afr reads may proceed; also fences B readback of
//           the PREVIOUS iteration against this iteration's B writes.
//     bar2: B complete -> readback may proceed; also fences A afr-reads
//           against the NEXT iteration's A writes.
//   Race-freedom: A-writes(i+1) happen after bar2(i), A-reads(i) before
//   bar2(i). B-readback-reads(i) drain via each wave's lgkmcnt(0) before it
//   passes bar1(i+1); B-writes(i+1) happen after bar1(i+1).
// ---------------------------------------------------------------------------
__global__ __launch_bounds__(256, 4) void k_layer(
    const h16* zin,                   // [ZROWS][128]
    h16* zout,                        // [ZROWS][128] (may equal zin)
    const double* __restrict__ gsp,   // stats of previous layer output
    double* __restrict__ gso,         // stats of this layer output
    const float* __restrict__ W,      // [128][128] fp32
    const float* __restrict__ gamma,  // [128]
    const float* __restrict__ beta)   // [128]
{
  __shared__ h16 actA[8192];          // 64 pts x 128 ch, XOR-swizzled
  __shared__ h16 actB[8192];
  __shared__ double red[256];

  const int t = threadIdx.x;
  const int w = t >> 6;
  const int lane = t & 63;
  const int ln = lane & 15;
  const int q = lane >> 4;
  const int G = (int)gridDim.x;

  // BN consts for this thread's 8 activation channels: c = (t&15)*8 + j
  float sc[8], sh[8];
  {
    const double n = (double)PP;
    const int cb = (t & 15) * 8;
#pragma unroll
    for (int j = 0; j < 8; ++j) {
      const int c = cb + j;
      const double mu = gsp[c] / n;
      const double var = gsp[128 + c] / n - mu * mu;
      const float rstd = (float)(1.0 / sqrt(var + 1e-5));
      sc[j] = rstd * gamma[c];
      sh[j] = beta[c] - (float)mu * sc[j];
    }
  }

  // Persistent W fragments (A-operand), wave w owns channels [w*32, w*32+32).
  // Permuted row mapping: fragment-row rr of mfma nt <-> channel
  // ob + (rr>>2)*8 + nt*4 + (rr&3)  => lane owns channels ob+q*8 .. +7.
  const int ob = w * 32;
  f16x8 wfr[2][4];
#pragma unroll
  for (int nt = 0; nt < 2; ++nt) {
    const int row_g = ob + (ln >> 2) * 8 + nt * 4 + (ln & 3);
    const float* wrow = W + (size_t)row_g * 128;
#pragma unroll
    for (int ks = 0; ks < 4; ++ks) {
      const float* src = wrow + ks * 32 + q * 8;
      const float4 aa = *(const float4*)src;
      const float4 bb = *(const float4*)(src + 4);
      f16x8 b;
      b[0] = (h16)aa.x; b[1] = (h16)aa.y; b[2] = (h16)aa.z; b[3] = (h16)aa.w;
      b[4] = (h16)bb.x; b[5] = (h16)bb.y; b[6] = (h16)bb.z; b[7] = (h16)bb.w;
      wfr[nt][ks] = b;
    }
  }

  float sp[8], qp[8];
#pragma unroll
  for (int i = 0; i < 8; ++i) { sp[i] = 0.f; qp[i] = 0.f; }

  // Address precompute (bytes). Swizzle family: chunk ^= (row & 7).
  // raw-load / act-write: thread owns rows (t>>4)+16s, chunk t&15.
  const size_t roff = (size_t)(t >> 4) * 128 + (size_t)(t & 15) * 8;  // h16
  const int wbase = (t >> 4) * 256 + (((t & 15) ^ ((t >> 4) & 7)) << 4);
  // afr read: row ln (+ot*16), chunk ks*4+q
  int raddr[4];
#pragma unroll
  for (int ks = 0; ks < 4; ++ks)
    raddr[ks] = ln * 256 + (((ks * 4 + q) ^ (ln & 7)) << 4);
  // out write: row ln (+ot*16), chunk w*4+q
  const int obase = ln * 256 + (((w * 4 + q) ^ (ln & 7)) << 4);
  // out readback: global chunk c = pass*256 + t -> row pass*16+(t>>4), k t&15
  const int rbase = (t >> 4) * 256 + (((t & 15) ^ ((t >> 4) & 7)) << 4);

  int stile = blockIdx.x;
  f16x8 raw[4];
  {
    const h16* src = zin + (size_t)stile * 8192 + roff;
#pragma unroll
    for (int s = 0; s < 4; ++s) raw[s] = *(const f16x8*)(src + s * 2048);
  }

  char* A = (char*)actA;
  char* B = (char*)actB;

  for (; stile < NSUPER; stile += G) {
    // 1. BN + sine on this thread's 4 chunks -> act buffer A
#pragma unroll
    for (int s = 0; s < 4; ++s) {
      f16x8 av;
#pragma unroll
      for (int j = 0; j < 8; ++j)
        av[j] = (h16)__sinf(fmaf((float)raw[s][j], sc[j], sh[j]));
      *(f16x8*)(A + (wbase + s * 4096)) = av;
    }

    // 2. depth-1 prefetch of next supertile into the freed raw regs
    {
      const int nxt = (stile + G < NSUPER) ? stile + G : NSUPER - 1;
      const h16* src = zin + (size_t)nxt * 8192 + roff;
#pragma unroll
      for (int s = 0; s < 4; ++s) raw[s] = *(const f16x8*)(src + s * 2048);
    }

    // 3. bar1 (LDS-only drain: prefetch stays in flight)
    asm volatile("s_waitcnt lgkmcnt(0)\n\ts_barrier" ::: "memory");

    // 4. MFMA per 16-pt subtile; stats; results -> out buffer B
#pragma unroll
    for (int ot = 0; ot < 4; ++ot) {
      f16x8 afr[4];
#pragma unroll
      for (int ks = 0; ks < 4; ++ks)
        afr[ks] = *(const f16x8*)(A + (ot * 4096 + raddr[ks]));

      f32x4 acc0 = (f32x4){0.f, 0.f, 0.f, 0.f};
      f32x4 acc1 = (f32x4){0.f, 0.f, 0.f, 0.f};
#pragma unroll
      for (int ks = 0; ks < 4; ++ks) {
        acc0 = __builtin_amdgcn_mfma_f32_16x16x32_f16(wfr[0][ks], afr[ks], acc0, 0, 0, 0);
        acc1 = __builtin_amdgcn_mfma_f32_16x16x32_f16(wfr[1][ks], afr[ks], acc1, 0, 0, 0);
      }

      const int p = stile * 64 + ot * 16 + ln;
      if (p < PP) {
#pragma unroll
        for (int r = 0; r < 4; ++r) {
          sp[r]     += acc0[r];
          qp[r]      = fmaf(acc0[r], acc0[r], qp[r]);
          sp[4 + r] += acc1[r];
          qp[4 + r]  = fmaf(acc1[r], acc1[r], qp[4 + r]);
        }
      }
      f16x8 o;
      o[0] = (h16)acc0[0]; o[1] = (h16)acc0[1]; o[2] = (h16)acc0[2]; o[3] = (h16)acc0[3];
      o[4] = (h16)acc1[0]; o[5] = (h16)acc1[1]; o[6] = (h16)acc1[2]; o[7] = (h16)acc1[3];
      *(f16x8*)(B + (ot * 4096 + obase)) = o;
    }

    // 5. bar2 (B complete; also releases A for next iteration's writes)
    asm volatile("s_waitcnt lgkmcnt(0)\n\ts_barrier" ::: "memory");

    // 6. readback + 1KB-contiguous stores (buffer padded: no guard needed)
    {
      const size_t zo = (size_t)stile * 8192;
#pragma unroll
      for (int pass = 0; pass < 4; ++pass) {
        const f16x8 v = *(const f16x8*)(B + (pass * 4096 + rbase));
        *(f16x8*)(zout + zo + (size_t)pass * 2048 + (size_t)t * 8) = v;
      }
    }
  }

  // stats: reduce over the 16 ln lanes; sp[r]<->ch ob+q*8+r, sp[4+r]<->+4
#pragma unroll
  for (int i = 0; i < 8; ++i) {
#pragma unroll
    for (int d = 1; d < 16; d <<= 1) {
      sp[i] += __shfl_xor(sp[i], d, 64);
      qp[i] += __shfl_xor(qp[i], d, 64);
    }
  }
  if (ln == 0) {
#pragma unroll
    for (int r = 0; r < 4; ++r) {
      const int c = ob + q * 8 + r;
      red[c]           = (double)sp[r];
      red[c + 4]       = (double)sp[4 + r];
      red[128 + c]     = (double)qp[r];
      red[128 + c + 4] = (double)qp[4 + r];
    }
  }
  __syncthreads();
  atomicAdd(&gso[t], red[t]);
}

// ---------------------------------------------------------------------------
// Fused final conv (128->1, BN7+sine) + softmax over K=20 + gather-weighted
// sum. One wave per m. (unchanged)
// ---------------------------------------------------------------------------
__global__ __launch_bounds__(256) void k_outf(
    const h16* __restrict__ z,         // [ZROWS][128]
    const double* __restrict__ gsp,    // stats of layer-7 output
    const float* __restrict__ gamma,   // [128] (layer 7)
    const float* __restrict__ beta,    // [128]
    const float* __restrict__ fw,      // [128]
    const float* __restrict__ fb,      // [1]
    const int* __restrict__ idx,       // [MM][KK]
    const float* __restrict__ xf,      // [NF][128]
    float* __restrict__ out)           // [MM][128]
{
  const int gw = (int)((blockIdx.x * 256 + threadIdx.x) >> 6);
  const int lane = (int)(threadIdx.x & 63);
  if (gw >= MM) return;
  const int m = gw;
  const int c0 = lane * 2;

  float scv[2], shv[2], fv[2];
#pragma unroll
  for (int j = 0; j < 2; ++j) {
    const int c = c0 + j;
    const double n = (double)PP;
    const double mu = gsp[c] / n;
    const double var = gsp[128 + c] / n - mu * mu;
    const float rstd = (float)(1.0 / sqrt(var + 1e-5));
    scv[j] = rstd * gamma[c];
    shv[j] = beta[c] - (float)mu * scv[j];
    fv[j] = fw[c];
  }
  const float fbv = fb[0];

  float l[KK];
#pragma unroll
  for (int k = 0; k < KK; ++k) {
    const h16* zp = z + (size_t)(m * KK + k) * 128 + c0;
    float part = fv[0] * __sinf(fmaf((float)zp[0], scv[0], shv[0]))
               + fv[1] * __sinf(fmaf((float)zp[1], scv[1], shv[1]));
#pragma unroll
    for (int d = 1; d < 64; d <<= 1) part += __shfl_xor(part, d, 64);
    l[k] = part + fbv;
  }

  float mx = l[0];
#pragma unroll
  for (int k = 1; k < KK; ++k) mx = fmaxf(mx, l[k]);
  float ssum = 0.f;
#pragma unroll
  for (int k = 0; k < KK; ++k) { l[k] = __expf(l[k] - mx); ssum += l[k]; }
  const float inv = 1.f / ssum;

  float a0 = 0.f, a1 = 0.f;
#pragma unroll
  for (int k = 0; k < KK; ++k) {
    const int r = idx[m * KK + k];
    const float wk = l[k] * inv;
    a0 = fmaf(wk, xf[r * 128 + lane], a0);
    a1 = fmaf(wk, xf[r * 128 + 64 + lane], a1);
  }
  out[m * 128 + lane] = a0;
  out[m * 128 + 64 + lane] = a1;
}

// ---------------------------------------------------------------------------
// Softmax over K=20 per m + gather (logits-array version, fallback path).
// ---------------------------------------------------------------------------
__global__ __launch_bounds__(256) void k_out(
    const float* __restrict__ logits,  // [PP]
    const int* __restrict__ idx,       // [MM][KK]
    const float* __restrict__ xf,      // [NF][128]
    float* __restrict__ out)           // [MM][128]
{
  const int gw = (int)((blockIdx.x * 256 + threadIdx.x) >> 6);
  const int lane = threadIdx.x & 63;
  if (gw >= MM) return;
  const int m = gw;

  float l[KK];
#pragma unroll
  for (int k = 0; k < KK; ++k) l[k] = logits[m * KK + k];
  float mx = l[0];
#pragma unroll
  for (int k = 1; k < KK; ++k) mx = fmaxf(mx, l[k]);
  float ssum = 0.f;
#pragma unroll
  for (int k = 0; k < KK; ++k) { l[k] = __expf(l[k] - mx); ssum += l[k]; }
  const float inv = 1.f / ssum;

  float a0 = 0.f, a1 = 0.f;
#pragma unroll
  for (int k = 0; k < KK; ++k) {
    const int r = idx[m * KK + k];
    const float wk = l[k] * inv;
    a0 = fmaf(wk, xf[r * 128 + lane], a0);
    a1 = fmaf(wk, xf[r * 128 + 64 + lane], a1);
  }
  out[m * 128 + lane] = a0;
  out[m * 128 + 64 + lane] = a1;
}

// ---------------------------------------------------------------------------
// Fallback (small workspace): recompute chain in registers per point.
// ---------------------------------------------------------------------------
__global__ __launch_bounds__(256) void k_chain(
    const float* __restrict__ up,
    const float* __restrict__ w0,
    const float* __restrict__ wc,
    const float* __restrict__ gam,
    const float* __restrict__ bet,
    const double* __restrict__ gs,
    double* __restrict__ gso,
    int jl, int mode,
    const float* __restrict__ fw,
    const float* __restrict__ fb,
    float* __restrict__ logits)
{
  __shared__ float sc_s[8][128], sh_s[8][128];
  __shared__ double bred[4][256];
  const int t = threadIdx.x;
  const int lane = t & 63;

  const int nbn = (mode == 0) ? jl : 8;
  for (int i = t; i < nbn * 128; i += 256) {
    const int L = i >> 7, c = i & 127;
    const double n = (double)PP;
    const double mu = gs[L * 256 + c] / n;
    const double var = gs[L * 256 + 128 + c] / n - mu * mu;
    const float rstd = (float)(1.0 / sqrt(var + 1e-5));
    const float sc = rstd * gam[L * 128 + c];
    sc_s[L][c] = sc;
    sh_s[L][c] = bet[L * 128 + c] - (float)mu * sc;
  }
  __syncthreads();

  double lS0 = 0, lS1 = 0, lQ0 = 0, lQ1 = 0;

  for (int p0 = blockIdx.x * 256; p0 < PP; p0 += gridDim.x * 256) {
    const int p = p0 + t;
    const bool act = p < PP;

    float a[128];
    {
      float u[7];
#pragma unroll
      for (int c = 0; c < 7; ++c) u[c] = act ? up[c * PP + p] : 0.f;
#pragma unroll 1
      for (int och = 0; och < 16; ++och) {
#pragma unroll
        for (int j = 0; j < 8; ++j) {
          float acc = 0.f;
#pragma unroll
          for (int c = 0; c < 7; ++c)
            acc = fmaf(w0[(och * 8 + j) * 7 + c], u[c], acc);
          a[och * 8 + j] = acc;
        }
      }
    }

#pragma unroll 1
    for (int L = 0; L < jl; ++L) {
#pragma unroll
      for (int c = 0; c < 128; ++c)
        a[c] = act ? __sinf(fmaf(a[c], sc_s[L][c], sh_s[L][c])) : 0.f;
      float b[128];
      const float* W = wc + (size_t)L * 128 * 128;
#pragma unroll 1
      for (int och = 0; och < 16; ++och) {
#pragma unroll
        for (int j = 0; j < 8; ++j) {
          float acc = 0.f;
#pragma unroll
          for (int c = 0; c < 128; ++c)
            acc = fmaf(W[(och * 8 + j) * 128 + c], a[c], acc);
          b[och * 8 + j] = acc;
        }
      }
#pragma unroll
      for (int c = 0; c < 128; ++c) a[c] = b[c];
    }

    if (mode == 0) {
#pragma unroll
      for (int o = 0; o < 128; ++o) {
        float s = a[o];
        float qv = a[o] * a[o];
#pragma unroll
        for (int d = 32; d > 0; d >>= 1) {
          s += __shfl_xor(s, d, 64);
          qv += __shfl_xor(qv, d, 64);
        }
        if ((o & 63) == lane) {
          if (o < 64) { lS0 += (double)s; lQ0 += (double)qv; }
          else        { lS1 += (double)s; lQ1 += (double)qv; }
        }
      }
    } else if (act) {
      float acc = fb[0];
#pragma unroll
      for (int c = 0; c < 128; ++c) {
        const float h = fmaf(a[c], sc_s[7][c], sh_s[7][c]);
        acc = fmaf(fw[c], __sinf(h), acc);
      }
      logits[p] = acc;
    }
  }

  if (mode == 0) {
    const int w = t >> 6;
    bred[w][lane]       = lS0;
    bred[w][64 + lane]  = lS1;
    bred[w][128 + lane] = lQ0;
    bred[w][192 + lane] = lQ1;
    __syncthreads();
    double v = bred[0][t] + bred[1][t] + bred[2][t] + bred[3][t];
    atomicAdd(&gso[t], v);
  }
}

// ---------------------------------------------------------------------------
extern "C" void kernel_launch(void* const* d_in, const int* in_sizes, int n_in,
                              void* d_out, int out_size, void* d_ws, size_t ws_size,
                              hipStream_t stream) {
  const float* xf  = (const float*)d_in[0];  // (1, N, 128)
  const float* up  = (const float*)d_in[1];  // (1, 7, M, K)  == [7][PP]
  const int*   idx = (const int*)d_in[2];    // (1, M, K)
  const float* w0  = (const float*)d_in[3];  // (128, 7)
  const float* wc  = (const float*)d_in[4];  // (7, 128, 128)
  const float* gam = (const float*)d_in[5];  // (8, 128)
  const float* bet = (const float*)d_in[6];  // (8, 128)
  const float* fw  = (const float*)d_in[7];  // (1, 128)
  const float* fb  = (const float*)d_in[8];  // (1,)
  float* out = (float*)d_out;

  char* ws = (char*)d_ws;
  const size_t zb     = (size_t)ZROWS * 128 * sizeof(h16); // 182,468,608 B
  const size_t statsb = 8 * 256 * sizeof(double);          // 16,384 B
  const int NB = 1024;
  const int nbo = (MM + 3) / 4;

  if (ws_size >= 2 * zb + statsb) {
    // Fast path A: ping-pong z buffers (separate HBM read/write streams).
    h16* z0 = (h16*)ws;
    h16* z1 = (h16*)(ws + zb);
    double* gs = (double*)(ws + 2 * zb);

    k_zero<<<1, 256, 0, stream>>>(gs);
    k_layer0<<<NB, 256, 0, stream>>>(up, w0, z0, gs);
    h16* cur = z0;
    for (int i = 1; i <= 7; ++i) {
      h16* nxt = (i & 1) ? z1 : z0;
      k_layer<<<NB, 256, 0, stream>>>(cur, nxt,
                                      gs + (size_t)(i - 1) * 256,
                                      gs + (size_t)i * 256,
                                      wc + (size_t)(i - 1) * 128 * 128,
                                      gam + (size_t)(i - 1) * 128,
                                      bet + (size_t)(i - 1) * 128);
      cur = nxt;
    }
    k_outf<<<nbo, 256, 0, stream>>>(cur, gs + 7 * 256, gam + 7 * 128,
                                    bet + 7 * 128, fw, fb, idx, xf, out);
  } else if (ws_size >= zb + statsb) {
    // Fast path B: in-place z (same kernels, zin == zout).
    h16* z = (h16*)ws;
    double* gs = (double*)(ws + zb);

    k_zero<<<1, 256, 0, stream>>>(gs);
    k_layer0<<<NB, 256, 0, stream>>>(up, w0, z, gs);
    for (int i = 1; i <= 7; ++i) {
      k_layer<<<NB, 256, 0, stream>>>(z, z,
                                      gs + (size_t)(i - 1) * 256,
                                      gs + (size_t)i * 256,
                                      wc + (size_t)(i - 1) * 128 * 128,
                                      gam + (size_t)(i - 1) * 128,
                                      bet + (size_t)(i - 1) * 128);
    }
    k_outf<<<nbo, 256, 0, stream>>>(z, gs + 7 * 256, gam + 7 * 128,
                                    bet + 7 * 128, fw, fb, idx, xf, out);
  } else {
    // Fallback: recompute chain, needs only ~2.9 MiB of workspace.
    double* gs = (double*)ws;
    float* logits = (float*)(ws + statsb);

    k_zero<<<1, 256, 0, stream>>>(gs);
    for (int j = 0; j <= 7; ++j) {
      k_chain<<<NB, 256, 0, stream>>>(up, w0, wc, gam, bet, gs,
                                      gs + (size_t)j * 256, j, 0,
                                      fw, fb, logits);
    }
    k_chain<<<NB, 256, 0, stream>>>(up, w0, wc, gam, bet, gs,
                                    nullptr, 7, 1, fw, fb, logits);
    k_out<<<nbo, 256, 0, stream>>>(logits, idx, xf, out);
  }
}

// Round 5
// 701.156 us; speedup vs baseline: 1.1804x; 1.0179x over previous
//
#include <hip/hip_runtime.h>

// Problem constants (from reference)
#define PP 712740      // M*K points
#define MM 35637       // M
#define KK 20          // K neighbors
#define NF 15872       // N points in x_feat
#define NTILES 44547   // ceil(PP/16) point-tiles of 16
#define NSUPER 11137   // ceil(PP/64) supertiles of 64 points
#define ZROWS (NSUPER * 64)   // 712768 padded rows (z buffers sized to this)
// FEAT = 128 channels, W0 = 1.0, EPS = 1e-5

typedef _Float16 h16;
typedef __attribute__((ext_vector_type(8))) _Float16 f16x8;
typedef __attribute__((ext_vector_type(4))) float f32x4;

// ---------------------------------------------------------------------------
// Zero the stats accumulators (8 layers x 256 doubles).
// ---------------------------------------------------------------------------
__global__ __launch_bounds__(256) void k_zero(double* __restrict__ gs) {
  const int t = threadIdx.x;
#pragma unroll
  for (int i = 0; i < 8; ++i) gs[i * 256 + t] = 0.0;
}

// ---------------------------------------------------------------------------
// Layer-0 STATS ONLY (no z0 write): conv0 outputs computed in registers,
// per-channel sum/sumsq accumulated. w0 is rounded to f16 here to match
// k_layer1's on-the-fly recomputation exactly.
// ---------------------------------------------------------------------------
__global__ __launch_bounds__(256) void k_stats0(
    const float* __restrict__ up,    // [7][PP]
    const float* __restrict__ w0,    // [128][7]
    double* __restrict__ gs)         // [256]: sum[128], sumsq[128]
{
  __shared__ float w0s[128 * 7];
  __shared__ double red[4][256];
  const int t = threadIdx.x;
  for (int i = t; i < 128 * 7; i += 256) w0s[i] = (float)(h16)w0[i];
  __syncthreads();

  const int w = t >> 6;
  const int lane = t & 63;
  const int ln = lane & 15;
  const int q = lane >> 4;

  float sp[32], qp[32];
#pragma unroll
  for (int i = 0; i < 32; ++i) { sp[i] = 0.f; qp[i] = 0.f; }

  const int gw = blockIdx.x * 4 + w;
  for (int tile = gw; tile < NTILES; tile += gridDim.x * 4) {
    const int p = tile * 16 + ln;
    const bool act = p < PP;
    float u[7];
#pragma unroll
    for (int c7 = 0; c7 < 7; ++c7) u[c7] = act ? up[(size_t)c7 * PP + p] : 0.f;

#pragma unroll
    for (int ks = 0; ks < 4; ++ks)
#pragma unroll
      for (int j = 0; j < 8; ++j) {
        const int c = ks * 32 + q * 8 + j;
        float acc = 0.f;
#pragma unroll
        for (int c7 = 0; c7 < 7; ++c7) acc = fmaf(w0s[c * 7 + c7], u[c7], acc);
        const int si = ks * 8 + j;
        sp[si] += acc;                 // acc == 0 for pad points (u == 0)
        qp[si] = fmaf(acc, acc, qp[si]);
      }
  }

#pragma unroll
  for (int i = 0; i < 32; ++i) {
#pragma unroll
    for (int d = 1; d < 16; d <<= 1) {
      sp[i] += __shfl_xor(sp[i], d, 64);
      qp[i] += __shfl_xor(qp[i], d, 64);
    }
  }
  if (ln == 0) {
#pragma unroll
    for (int ks = 0; ks < 4; ++ks)
#pragma unroll
      for (int j = 0; j < 8; ++j) {
        const int c = ks * 32 + q * 8 + j;
        red[w][c] = (double)sp[ks * 8 + j];
        red[w][128 + c] = (double)qp[ks * 8 + j];
      }
  }
  __syncthreads();
  double v = red[0][t] + red[1][t] + red[2][t] + red[3][t];
  atomicAdd(&gs[t], v);
}

// ---------------------------------------------------------------------------
// Fused layer 0+1: recomputes conv0 on the fly from up (7 f16 FMAs/elem,
// w0 persistent in 28 VGPRs), applies BN0+sine, then the standard MFMA
// supertile pipeline (identical to k_layer). Eliminates the 182MB z0 write
// AND the 182MB z0 read. Output (layer-1 pre-BN) -> zout + gs1 stats.
// ---------------------------------------------------------------------------
__global__ __launch_bounds__(256, 3) void k_layer1(
    const float* __restrict__ up,     // [7][PP]
    const float* __restrict__ w0,     // [128][7]
    h16* __restrict__ zout,           // [ZROWS][128]
    const double* __restrict__ gsp,   // gs[0] (conv0-output stats)
    double* __restrict__ gso,         // gs[1]
    const float* __restrict__ W,      // [128][128] fp32 (convs_w[0])
    const float* __restrict__ gamma,  // [128] (gammas[0])
    const float* __restrict__ beta)   // [128]
{
  __shared__ h16 actA[8192];          // 64 pts x 128 ch, XOR-swizzled
  __shared__ h16 actB[8192];
  __shared__ double red[256];

  const int t = threadIdx.x;
  const int w = t >> 6;
  const int lane = t & 63;
  const int ln = lane & 15;
  const int q = lane >> 4;
  const int G = (int)gridDim.x;

  // BN consts for this thread's 8 activation channels: c = (t&15)*8 + j
  float sc[8], sh[8];
  {
    const double n = (double)PP;
    const int cb = (t & 15) * 8;
#pragma unroll
    for (int j = 0; j < 8; ++j) {
      const int c = cb + j;
      const double mu = gsp[c] / n;
      const double var = gsp[128 + c] / n - mu * mu;
      const float rstd = (float)(1.0 / sqrt(var + 1e-5));
      sc[j] = rstd * gamma[c];
      sh[j] = beta[c] - (float)mu * sc[j];
    }
  }

  // w0 for this thread's 8 channels, f16 (matches k_stats0 rounding)
  h16 w0h[7][8];
  {
    const int cb = (t & 15) * 8;
#pragma unroll
    for (int c7 = 0; c7 < 7; ++c7)
#pragma unroll
      for (int j = 0; j < 8; ++j)
        w0h[c7][j] = (h16)w0[(cb + j) * 7 + c7];
  }

  // Persistent W fragments (A-operand), wave w owns channels [w*32, w*32+32).
  const int ob = w * 32;
  f16x8 wfr[2][4];
#pragma unroll
  for (int nt = 0; nt < 2; ++nt) {
    const int row_g = ob + (ln >> 2) * 8 + nt * 4 + (ln & 3);
    const float* wrow = W + (size_t)row_g * 128;
#pragma unroll
    for (int ks = 0; ks < 4; ++ks) {
      const float* src = wrow + ks * 32 + q * 8;
      const float4 aa = *(const float4*)src;
      const float4 bb = *(const float4*)(src + 4);
      f16x8 b;
      b[0] = (h16)aa.x; b[1] = (h16)aa.y; b[2] = (h16)aa.z; b[3] = (h16)aa.w;
      b[4] = (h16)bb.x; b[5] = (h16)bb.y; b[6] = (h16)bb.z; b[7] = (h16)bb.w;
      wfr[nt][ks] = b;
    }
  }

  float sp[8], qp[8];
#pragma unroll
  for (int i = 0; i < 8; ++i) { sp[i] = 0.f; qp[i] = 0.f; }

  // LDS addressing (identical swizzle family to k_layer)
  const int wbase = (t >> 4) * 256 + (((t & 15) ^ ((t >> 4) & 7)) << 4);
  int raddr[4];
#pragma unroll
  for (int ks = 0; ks < 4; ++ks)
    raddr[ks] = ln * 256 + (((ks * 4 + q) ^ (ln & 7)) << 4);
  const int obase = ln * 256 + (((w * 4 + q) ^ (ln & 7)) << 4);
  const int rbase = (t >> 4) * 256 + (((t & 15) ^ ((t >> 4) & 7)) << 4);

  char* A = (char*)actA;
  char* B = (char*)actB;

  for (int stile = blockIdx.x; stile < NSUPER; stile += G) {
    // 1. load up for this thread's 4 points
    float u[4][7];
#pragma unroll
    for (int s = 0; s < 4; ++s) {
      const int p = stile * 64 + (t >> 4) + 16 * s;
      const bool act = p < PP;
#pragma unroll
      for (int c7 = 0; c7 < 7; ++c7)
        u[s][c7] = act ? up[(size_t)c7 * PP + p] : 0.f;
    }

    // 2. conv0 (f16 weights) + BN0 + sine -> act buffer A
#pragma unroll
    for (int s = 0; s < 4; ++s) {
      f16x8 av;
#pragma unroll
      for (int j = 0; j < 8; ++j) {
        float acc = 0.f;
#pragma unroll
        for (int c7 = 0; c7 < 7; ++c7)
          acc = fmaf((float)w0h[c7][j], u[s][c7], acc);
        av[j] = (h16)__sinf(fmaf(acc, sc[j], sh[j]));
      }
      *(f16x8*)(A + (wbase + s * 4096)) = av;
    }

    // 3. bar1 (LDS-only drain)
    asm volatile("s_waitcnt lgkmcnt(0)\n\ts_barrier" ::: "memory");

    // 4. MFMA per 16-pt subtile; stats; results -> out buffer B
#pragma unroll
    for (int ot = 0; ot < 4; ++ot) {
      f16x8 afr[4];
#pragma unroll
      for (int ks = 0; ks < 4; ++ks)
        afr[ks] = *(const f16x8*)(A + (ot * 4096 + raddr[ks]));

      f32x4 acc0 = (f32x4){0.f, 0.f, 0.f, 0.f};
      f32x4 acc1 = (f32x4){0.f, 0.f, 0.f, 0.f};
#pragma unroll
      for (int ks = 0; ks < 4; ++ks) {
        acc0 = __builtin_amdgcn_mfma_f32_16x16x32_f16(wfr[0][ks], afr[ks], acc0, 0, 0, 0);
        acc1 = __builtin_amdgcn_mfma_f32_16x16x32_f16(wfr[1][ks], afr[ks], acc1, 0, 0, 0);
      }

      const int p = stile * 64 + ot * 16 + ln;
      if (p < PP) {
#pragma unroll
        for (int r = 0; r < 4; ++r) {
          sp[r]     += acc0[r];
          qp[r]      = fmaf(acc0[r], acc0[r], qp[r]);
          sp[4 + r] += acc1[r];
          qp[4 + r]  = fmaf(acc1[r], acc1[r], qp[4 + r]);
        }
      }
      f16x8 o;
      o[0] = (h16)acc0[0]; o[1] = (h16)acc0[1]; o[2] = (h16)acc0[2]; o[3] = (h16)acc0[3];
      o[4] = (h16)acc1[0]; o[5] = (h16)acc1[1]; o[6] = (h16)acc1[2]; o[7] = (h16)acc1[3];
      *(f16x8*)(B + (ot * 4096 + obase)) = o;
    }

    // 5. bar2 (B complete; releases A)
    asm volatile("s_waitcnt lgkmcnt(0)\n\ts_barrier" ::: "memory");

    // 6. readback + 1KB-contiguous stores
    {
      const size_t zo = (size_t)stile * 8192;
#pragma unroll
      for (int pass = 0; pass < 4; ++pass) {
        const f16x8 v = *(const f16x8*)(B + (pass * 4096 + rbase));
        *(f16x8*)(zout + zo + (size_t)pass * 2048 + (size_t)t * 8) = v;
      }
    }
  }

  // stats reduction
#pragma unroll
  for (int i = 0; i < 8; ++i) {
#pragma unroll
    for (int d = 1; d < 16; d <<= 1) {
      sp[i] += __shfl_xor(sp[i], d, 64);
      qp[i] += __shfl_xor(qp[i], d, 64);
    }
  }
  if (ln == 0) {
#pragma unroll
    for (int r = 0; r < 4; ++r) {
      const int c = ob + q * 8 + r;
      red[c]           = (double)sp[r];
      red[c + 4]       = (double)sp[4 + r];
      red[128 + c]     = (double)qp[r];
      red[128 + c + 4] = (double)qp[4 + r];
    }
  }
  __syncthreads();
  atomicAdd(&gso[t], red[t]);
}

// ---------------------------------------------------------------------------
// Middle layer (x6, layers 2..7), MFMA supertiles. UNCHANGED from the
// verified round-4 kernel.
// ---------------------------------------------------------------------------
__global__ __launch_bounds__(256, 4) void k_layer(
    const h16* zin,                   // [ZROWS][128]
    h16* zout,                        // [ZROWS][128] (may equal zin)
    const double* __restrict__ gsp,
    double* __restrict__ gso,
    const float* __restrict__ W,
    const float* __restrict__ gamma,
    const float* __restrict__ beta)
{
  __shared__ h16 actA[8192];
  __shared__ h16 actB[8192];
  __shared__ double red[256];

  const int t = threadIdx.x;
  const int w = t >> 6;
  const int lane = t & 63;
  const int ln = lane & 15;
  const int q = lane >> 4;
  const int G = (int)gridDim.x;

  float sc[8], sh[8];
  {
    const double n = (double)PP;
    const int cb = (t & 15) * 8;
#pragma unroll
    for (int j = 0; j < 8; ++j) {
      const int c = cb + j;
      const double mu = gsp[c] / n;
      const double var = gsp[128 + c] / n - mu * mu;
      const float rstd = (float)(1.0 / sqrt(var + 1e-5));
      sc[j] = rstd * gamma[c];
      sh[j] = beta[c] - (float)mu * sc[j];
    }
  }

  const int ob = w * 32;
  f16x8 wfr[2][4];
#pragma unroll
  for (int nt = 0; nt < 2; ++nt) {
    const int row_g = ob + (ln >> 2) * 8 + nt * 4 + (ln & 3);
    const float* wrow = W + (size_t)row_g * 128;
#pragma unroll
    for (int ks = 0; ks < 4; ++ks) {
      const float* src = wrow + ks * 32 + q * 8;
      const float4 aa = *(const float4*)src;
      const float4 bb = *(const float4*)(src + 4);
      f16x8 b;
      b[0] = (h16)aa.x; b[1] = (h16)aa.y; b[2] = (h16)aa.z; b[3] = (h16)aa.w;
      b[4] = (h16)bb.x; b[5] = (h16)bb.y; b[6] = (h16)bb.z; b[7] = (h16)bb.w;
      wfr[nt][ks] = b;
    }
  }

  float sp[8], qp[8];
#pragma unroll
  for (int i = 0; i < 8; ++i) { sp[i] = 0.f; qp[i] = 0.f; }

  const size_t roff = (size_t)(t >> 4) * 128 + (size_t)(t & 15) * 8;
  const int wbase = (t >> 4) * 256 + (((t & 15) ^ ((t >> 4) & 7)) << 4);
  int raddr[4];
#pragma unroll
  for (int ks = 0; ks < 4; ++ks)
    raddr[ks] = ln * 256 + (((ks * 4 + q) ^ (ln & 7)) << 4);
  const int obase = ln * 256 + (((w * 4 + q) ^ (ln & 7)) << 4);
  const int rbase = (t >> 4) * 256 + (((t & 15) ^ ((t >> 4) & 7)) << 4);

  int stile = blockIdx.x;
  f16x8 raw[4];
  {
    const h16* src = zin + (size_t)stile * 8192 + roff;
#pragma unroll
    for (int s = 0; s < 4; ++s) raw[s] = *(const f16x8*)(src + s * 2048);
  }

  char* A = (char*)actA;
  char* B = (char*)actB;

  for (; stile < NSUPER; stile += G) {
#pragma unroll
    for (int s = 0; s < 4; ++s) {
      f16x8 av;
#pragma unroll
      for (int j = 0; j < 8; ++j)
        av[j] = (h16)__sinf(fmaf((float)raw[s][j], sc[j], sh[j]));
      *(f16x8*)(A + (wbase + s * 4096)) = av;
    }

    {
      const int nxt = (stile + G < NSUPER) ? stile + G : NSUPER - 1;
      const h16* src = zin + (size_t)nxt * 8192 + roff;
#pragma unroll
      for (int s = 0; s < 4; ++s) raw[s] = *(const f16x8*)(src + s * 2048);
    }

    asm volatile("s_waitcnt lgkmcnt(0)\n\ts_barrier" ::: "memory");

#pragma unroll
    for (int ot = 0; ot < 4; ++ot) {
      f16x8 afr[4];
#pragma unroll
      for (int ks = 0; ks < 4; ++ks)
        afr[ks] = *(const f16x8*)(A + (ot * 4096 + raddr[ks]));

      f32x4 acc0 = (f32x4){0.f, 0.f, 0.f, 0.f};
      f32x4 acc1 = (f32x4){0.f, 0.f, 0.f, 0.f};
#pragma unroll
      for (int ks = 0; ks < 4; ++ks) {
        acc0 = __builtin_amdgcn_mfma_f32_16x16x32_f16(wfr[0][ks], afr[ks], acc0, 0, 0, 0);
        acc1 = __builtin_amdgcn_mfma_f32_16x16x32_f16(wfr[1][ks], afr[ks], acc1, 0, 0, 0);
      }

      const int p = stile * 64 + ot * 16 + ln;
      if (p < PP) {
#pragma unroll
        for (int r = 0; r < 4; ++r) {
          sp[r]     += acc0[r];
          qp[r]      = fmaf(acc0[r], acc0[r], qp[r]);
          sp[4 + r] += acc1[r];
          qp[4 + r]  = fmaf(acc1[r], acc1[r], qp[4 + r]);
        }
      }
      f16x8 o;
      o[0] = (h16)acc0[0]; o[1] = (h16)acc0[1]; o[2] = (h16)acc0[2]; o[3] = (h16)acc0[3];
      o[4] = (h16)acc1[0]; o[5] = (h16)acc1[1]; o[6] = (h16)acc1[2]; o[7] = (h16)acc1[3];
      *(f16x8*)(B + (ot * 4096 + obase)) = o;
    }

    asm volatile("s_waitcnt lgkmcnt(0)\n\ts_barrier" ::: "memory");

    {
      const size_t zo = (size_t)stile * 8192;
#pragma unroll
      for (int pass = 0; pass < 4; ++pass) {
        const f16x8 v = *(const f16x8*)(B + (pass * 4096 + rbase));
        *(f16x8*)(zout + zo + (size_t)pass * 2048 + (size_t)t * 8) = v;
      }
    }
  }

#pragma unroll
  for (int i = 0; i < 8; ++i) {
#pragma unroll
    for (int d = 1; d < 16; d <<= 1) {
      sp[i] += __shfl_xor(sp[i], d, 64);
      qp[i] += __shfl_xor(qp[i], d, 64);
    }
  }
  if (ln == 0) {
#pragma unroll
    for (int r = 0; r < 4; ++r) {
      const int c = ob + q * 8 + r;
      red[c]           = (double)sp[r];
      red[c + 4]       = (double)sp[4 + r];
      red[128 + c]     = (double)qp[r];
      red[128 + c + 4] = (double)qp[4 + r];
    }
  }
  __syncthreads();
  atomicAdd(&gso[t], red[t]);
}

// ---------------------------------------------------------------------------
// Fused final conv (128->1, BN7+sine) + softmax over K=20 + gather. One wave
// per m. Reworked loads: 4 rows per instruction (f16x8/lane, 1KB/wave).
// Lane (q,ln) reads row 4g+q, channels ln*8..+7; in-group butterfly gives
// the row logit; 3 xor-shuffles reconstruct all 20 logits per lane.
// ---------------------------------------------------------------------------
__global__ __launch_bounds__(256) void k_outf(
    const h16* __restrict__ z,         // [ZROWS][128]
    const double* __restrict__ gsp,    // stats of layer-7 output
    const float* __restrict__ gamma,   // [128] (layer 7)
    const float* __restrict__ beta,    // [128]
    const float* __restrict__ fw,      // [128]
    const float* __restrict__ fb,      // [1]
    const int* __restrict__ idx,       // [MM][KK]
    const float* __restrict__ xf,      // [NF][128]
    float* __restrict__ out)           // [MM][128]
{
  const int gw = (int)((blockIdx.x * 256 + threadIdx.x) >> 6);
  const int lane = (int)(threadIdx.x & 63);
  if (gw >= MM) return;
  const int m = gw;
  const int ln = lane & 15;
  const int q = lane >> 4;
  const int c0 = ln * 8;

  float scv[8], shv[8], fv[8];
#pragma unroll
  for (int j = 0; j < 8; ++j) {
    const int c = c0 + j;
    const double n = (double)PP;
    const double mu = gsp[c] / n;
    const double var = gsp[128 + c] / n - mu * mu;
    const float rstd = (float)(1.0 / sqrt(var + 1e-5));
    scv[j] = rstd * gamma[c];
    shv[j] = beta[c] - (float)mu * scv[j];
    fv[j] = fw[c];
  }
  const float fbv = fb[0];

  // logits for rows 4g+q (all lanes of group q end up with the same value)
  float lg[5];
#pragma unroll
  for (int g = 0; g < 5; ++g) {
    const h16* zp = z + (size_t)(m * KK + g * 4 + q) * 128 + c0;
    const f16x8 raw = *(const f16x8*)zp;
    float part = 0.f;
#pragma unroll
    for (int j = 0; j < 8; ++j)
      part = fmaf(fv[j], __sinf(fmaf((float)raw[j], scv[j], shv[j])), part);
    part += __shfl_xor(part, 1, 64);
    part += __shfl_xor(part, 2, 64);
    part += __shfl_xor(part, 4, 64);
    part += __shfl_xor(part, 8, 64);
    lg[g] = part + fbv;
  }

  // reconstruct logits of the other 3 groups: l{e}[g] = row 4g + (q^e)
  float l1[5], l2[5], l3[5];
#pragma unroll
  for (int g = 0; g < 5; ++g) {
    l1[g] = __shfl_xor(lg[g], 16, 64);
    l2[g] = __shfl_xor(lg[g], 32, 64);
    l3[g] = __shfl_xor(l1[g], 32, 64);
  }

  float mx = lg[0];
#pragma unroll
  for (int g = 0; g < 5; ++g) {
    mx = fmaxf(mx, lg[g]); mx = fmaxf(mx, l1[g]);
    mx = fmaxf(mx, l2[g]); mx = fmaxf(mx, l3[g]);
  }
  float w0e[5], w1e[5], w2e[5], w3e[5];
  float ssum = 0.f;
#pragma unroll
  for (int g = 0; g < 5; ++g) {
    w0e[g] = __expf(lg[g] - mx); ssum += w0e[g];
    w1e[g] = __expf(l1[g] - mx); ssum += w1e[g];
    w2e[g] = __expf(l2[g] - mx); ssum += w2e[g];
    w3e[g] = __expf(l3[g] - mx); ssum += w3e[g];
  }
  const float inv = 1.f / ssum;

  float a0 = 0.f, a1 = 0.f;
#pragma unroll
  for (int g = 0; g < 5; ++g) {
#pragma unroll
    for (int e = 0; e < 4; ++e) {
      const int k = 4 * g + (q ^ e);
      const float we = (e == 0 ? w0e[g] : e == 1 ? w1e[g] : e == 2 ? w2e[g] : w3e[g]);
      const int r = idx[m * KK + k];
      const float wk = we * inv;
      a0 = fmaf(wk, xf[r * 128 + lane], a0);
      a1 = fmaf(wk, xf[r * 128 + 64 + lane], a1);
    }
  }
  out[m * 128 + lane] = a0;
  out[m * 128 + 64 + lane] = a1;
}

// ---------------------------------------------------------------------------
// Softmax over K=20 per m + gather (logits-array version, fallback path).
// ---------------------------------------------------------------------------
__global__ __launch_bounds__(256) void k_out(
    const float* __restrict__ logits,  // [PP]
    const int* __restrict__ idx,       // [MM][KK]
    const float* __restrict__ xf,      // [NF][128]
    float* __restrict__ out)           // [MM][128]
{
  const int gw = (int)((blockIdx.x * 256 + threadIdx.x) >> 6);
  const int lane = threadIdx.x & 63;
  if (gw >= MM) return;
  const int m = gw;

  float l[KK];
#pragma unroll
  for (int k = 0; k < KK; ++k) l[k] = logits[m * KK + k];
  float mx = l[0];
#pragma unroll
  for (int k = 1; k < KK; ++k) mx = fmaxf(mx, l[k]);
  float ssum = 0.f;
#pragma unroll
  for (int k = 0; k < KK; ++k) { l[k] = __expf(l[k] - mx); ssum += l[k]; }
  const float inv = 1.f / ssum;

  float a0 = 0.f, a1 = 0.f;
#pragma unroll
  for (int k = 0; k < KK; ++k) {
    const int r = idx[m * KK + k];
    const float wk = l[k] * inv;
    a0 = fmaf(wk, xf[r * 128 + lane], a0);
    a1 = fmaf(wk, xf[r * 128 + 64 + lane], a1);
  }
  out[m * 128 + lane] = a0;
  out[m * 128 + 64 + lane] = a1;
}

// ---------------------------------------------------------------------------
// Fallback (small workspace): recompute chain in registers per point.
// ---------------------------------------------------------------------------
__global__ __launch_bounds__(256) void k_chain(
    const float* __restrict__ up,
    const float* __restrict__ w0,
    const float* __restrict__ wc,
    const float* __restrict__ gam,
    const float* __restrict__ bet,
    const double* __restrict__ gs,
    double* __restrict__ gso,
    int jl, int mode,
    const float* __restrict__ fw,
    const float* __restrict__ fb,
    float* __restrict__ logits)
{
  __shared__ float sc_s[8][128], sh_s[8][128];
  __shared__ double bred[4][256];
  const int t = threadIdx.x;
  const int lane = t & 63;

  const int nbn = (mode == 0) ? jl : 8;
  for (int i = t; i < nbn * 128; i += 256) {
    const int L = i >> 7, c = i & 127;
    const double n = (double)PP;
    const double mu = gs[L * 256 + c] / n;
    const double var = gs[L * 256 + 128 + c] / n - mu * mu;
    const float rstd = (float)(1.0 / sqrt(var + 1e-5));
    const float sc = rstd * gam[L * 128 + c];
    sc_s[L][c] = sc;
    sh_s[L][c] = bet[L * 128 + c] - (float)mu * sc;
  }
  __syncthreads();

  double lS0 = 0, lS1 = 0, lQ0 = 0, lQ1 = 0;

  for (int p0 = blockIdx.x * 256; p0 < PP; p0 += gridDim.x * 256) {
    const int p = p0 + t;
    const bool act = p < PP;

    float a[128];
    {
      float u[7];
#pragma unroll
      for (int c = 0; c < 7; ++c) u[c] = act ? up[c * PP + p] : 0.f;
#pragma unroll 1
      for (int och = 0; och < 16; ++och) {
#pragma unroll
        for (int j = 0; j < 8; ++j) {
          float acc = 0.f;
#pragma unroll
          for (int c = 0; c < 7; ++c)
            acc = fmaf(w0[(och * 8 + j) * 7 + c], u[c], acc);
          a[och * 8 + j] = acc;
        }
      }
    }

#pragma unroll 1
    for (int L = 0; L < jl; ++L) {
#pragma unroll
      for (int c = 0; c < 128; ++c)
        a[c] = act ? __sinf(fmaf(a[c], sc_s[L][c], sh_s[L][c])) : 0.f;
      float b[128];
      const float* W = wc + (size_t)L * 128 * 128;
#pragma unroll 1
      for (int och = 0; och < 16; ++och) {
#pragma unroll
        for (int j = 0; j < 8; ++j) {
          float acc = 0.f;
#pragma unroll
          for (int c = 0; c < 128; ++c)
            acc = fmaf(W[(och * 8 + j) * 128 + c], a[c], acc);
          b[och * 8 + j] = acc;
        }
      }
#pragma unroll
      for (int c = 0; c < 128; ++c) a[c] = b[c];
    }

    if (mode == 0) {
#pragma unroll
      for (int o = 0; o < 128; ++o) {
        float s = a[o];
        float qv = a[o] * a[o];
#pragma unroll
        for (int d = 32; d > 0; d >>= 1) {
          s += __shfl_xor(s, d, 64);
          qv += __shfl_xor(qv, d, 64);
        }
        if ((o & 63) == lane) {
          if (o < 64) { lS0 += (double)s; lQ0 += (double)qv; }
          else        { lS1 += (double)s; lQ1 += (double)qv; }
        }
      }
    } else if (act) {
      float acc = fb[0];
#pragma unroll
      for (int c = 0; c < 128; ++c) {
        const float h = fmaf(a[c], sc_s[7][c], sh_s[7][c]);
        acc = fmaf(fw[c], __sinf(h), acc);
      }
      logits[p] = acc;
    }
  }

  if (mode == 0) {
    const int w = t >> 6;
    bred[w][lane]       = lS0;
    bred[w][64 + lane]  = lS1;
    bred[w][128 + lane] = lQ0;
    bred[w][192 + lane] = lQ1;
    __syncthreads();
    double v = bred[0][t] + bred[1][t] + bred[2][t] + bred[3][t];
    atomicAdd(&gso[t], v);
  }
}

// ---------------------------------------------------------------------------
extern "C" void kernel_launch(void* const* d_in, const int* in_sizes, int n_in,
                              void* d_out, int out_size, void* d_ws, size_t ws_size,
                              hipStream_t stream) {
  const float* xf  = (const float*)d_in[0];  // (1, N, 128)
  const float* up  = (const float*)d_in[1];  // (1, 7, M, K)  == [7][PP]
  const int*   idx = (const int*)d_in[2];    // (1, M, K)
  const float* w0  = (const float*)d_in[3];  // (128, 7)
  const float* wc  = (const float*)d_in[4];  // (7, 128, 128)
  const float* gam = (const float*)d_in[5];  // (8, 128)
  const float* bet = (const float*)d_in[6];  // (8, 128)
  const float* fw  = (const float*)d_in[7];  // (1, 128)
  const float* fb  = (const float*)d_in[8];  // (1,)
  float* out = (float*)d_out;

  char* ws = (char*)d_ws;
  const size_t zb     = (size_t)ZROWS * 128 * sizeof(h16); // 182,468,608 B
  const size_t statsb = 8 * 256 * sizeof(double);          // 16,384 B
  const int NB = 1024;
  const int nbo = (MM + 3) / 4;

  if (ws_size >= 2 * zb + statsb) {
    // Fast path A: ping-pong z buffers.
    h16* z0 = (h16*)ws;
    h16* z1 = (h16*)(ws + zb);
    double* gs = (double*)(ws + 2 * zb);

    k_zero<<<1, 256, 0, stream>>>(gs);
    k_stats0<<<NB, 256, 0, stream>>>(up, w0, gs);
    k_layer1<<<NB, 256, 0, stream>>>(up, w0, z0, gs, gs + 256,
                                     wc, gam, bet);
    h16* cur = z0;
    for (int i = 2; i <= 7; ++i) {
      h16* nxt = (cur == z0) ? z1 : z0;
      k_layer<<<NB, 256, 0, stream>>>(cur, nxt,
                                      gs + (size_t)(i - 1) * 256,
                                      gs + (size_t)i * 256,
                                      wc + (size_t)(i - 1) * 128 * 128,
                                      gam + (size_t)(i - 1) * 128,
                                      bet + (size_t)(i - 1) * 128);
      cur = nxt;
    }
    k_outf<<<nbo, 256, 0, stream>>>(cur, gs + 7 * 256, gam + 7 * 128,
                                    bet + 7 * 128, fw, fb, idx, xf, out);
  } else if (ws_size >= zb + statsb) {
    // Fast path B: in-place z.
    h16* z = (h16*)ws;
    double* gs = (double*)(ws + zb);

    k_zero<<<1, 256, 0, stream>>>(gs);
    k_stats0<<<NB, 256, 0, stream>>>(up, w0, gs);
    k_layer1<<<NB, 256, 0, stream>>>(up, w0, z, gs, gs + 256,
                                     wc, gam, bet);
    for (int i = 2; i <= 7; ++i) {
      k_layer<<<NB, 256, 0, stream>>>(z, z,
                                      gs + (size_t)(i - 1) * 256,
                                      gs + (size_t)i * 256,
                                      wc + (size_t)(i - 1) * 128 * 128,
                                      gam + (size_t)(i - 1) * 128,
                                      bet + (size_t)(i - 1) * 128);
    }
    k_outf<<<nbo, 256, 0, stream>>>(z, gs + 7 * 256, gam + 7 * 128,
                                    bet + 7 * 128, fw, fb, idx, xf, out);
  } else {
    // Fallback: recompute chain, needs only ~2.9 MiB of workspace.
    double* gs = (double*)ws;
    float* logits = (float*)(ws + statsb);

    k_zero<<<1, 256, 0, stream>>>(gs);
    for (int j = 0; j <= 7; ++j) {
      k_chain<<<NB, 256, 0, stream>>>(up, w0, wc, gam, bet, gs,
                                      gs + (size_t)j * 256, j, 0,
                                      fw, fb, logits);
    }
    k_chain<<<NB, 256, 0, stream>>>(up, w0, wc, gam, bet, gs,
                                    nullptr, 7, 1, fw, fb, logits);
    k_out<<<nbo, 256, 0, stream>>>(logits, idx, xf, out);
  }
}